// Round 5
// baseline (650.978 us; speedup 1.0000x reference)
//
#include <hip/hip_runtime.h>
#include <hip/hip_bf16.h>
#include <hip/hip_fp16.h>

// GQNN: 2-layer GraphSAGE (mean aggr) + fc head. N=100k, E=3.2M, d=64/65.
// R5: force VGPR-addressed gathers. R4 evidence: ~50k wave-serial cycles per
// node (258us) regardless of bytes (fp32->fp16) or unroll (4->8) => gathers
// are serialized one-full-latency-each. Cause: __shfl with uniform lane ->
// v_readlane -> SGPR base; SGPR_Count=48 => address-SGPR recycling forces
// vmcnt(0) between gathers. Fix: ds_bpermute broadcast (divergent result,
// stays in VGPR) + per-lane 64-bit VGPR addresses => vmcnt(N) pipelining.
// Everything else unchanged from R4 (fp16 rows, build kernels from R2).

#define WAVES_PER_BLOCK 16
#define LAYER_BLOCK (WAVES_PER_BLOCK * 64)
#define LAYER_GRID 512

#define BSH 7                    // bucket shift: 128 nodes per bucket
#define NBKT 782                 // ceil(100000 / 128)
#define NBLK 256                 // binning blocks

// ---------------- CSR build (unchanged from R2) ----------------

__global__ __launch_bounds__(256) void k_hist(const int* __restrict__ dst,
                                              int* __restrict__ histT, int E) {
    __shared__ int h[NBKT];
    for (int i = threadIdx.x; i < NBKT; i += 256) h[i] = 0;
    __syncthreads();
    int per = (E + NBLK - 1) / NBLK;
    int lo = blockIdx.x * per;
    int hi = lo + per; if (hi > E) hi = E;
    for (int e = lo + threadIdx.x; e < hi; e += 256)
        atomicAdd(&h[dst[e] >> BSH], 1);
    __syncthreads();
    for (int k = threadIdx.x; k < NBKT; k += 256)
        histT[k * NBLK + blockIdx.x] = h[k];
}

__global__ __launch_bounds__(NBLK) void k_scanblk(int* __restrict__ histT,
                                                  int* __restrict__ btot) {
    __shared__ int s[NBLK];
    int k = blockIdx.x, t = threadIdx.x;
    int v = histT[k * NBLK + t];
    s[t] = v;
    __syncthreads();
    for (int off = 1; off < NBLK; off <<= 1) {
        int u = (t >= off) ? s[t - off] : 0;
        __syncthreads();
        s[t] += u;
        __syncthreads();
    }
    histT[k * NBLK + t] = s[t] - v;
    if (t == NBLK - 1) btot[k] = s[t];
}

__global__ __launch_bounds__(1024) void k_scanbkt(const int* __restrict__ btot,
                                                  int* __restrict__ bstart) {
    __shared__ int s[1024];
    int t = threadIdx.x;
    int v = (t < NBKT) ? btot[t] : 0;
    s[t] = v;
    __syncthreads();
    for (int off = 1; off < 1024; off <<= 1) {
        int u = (t >= off) ? s[t - off] : 0;
        __syncthreads();
        s[t] += u;
        __syncthreads();
    }
    if (t < NBKT) bstart[t] = s[t] - v;
    if (t == NBKT - 1) bstart[NBKT] = s[t];
}

__global__ __launch_bounds__(256) void k_scatter(const int* __restrict__ src,
                                                 const int* __restrict__ dst,
                                                 const int* __restrict__ histT,
                                                 const int* __restrict__ bstart,
                                                 int* __restrict__ binned, int E) {
    __shared__ int cur[NBKT];
    int b = blockIdx.x;
    for (int k = threadIdx.x; k < NBKT; k += 256)
        cur[k] = bstart[k] + histT[k * NBLK + b];
    __syncthreads();
    int per = (E + NBLK - 1) / NBLK;
    int lo = b * per;
    int hi = lo + per; if (hi > E) hi = E;
    for (int e = lo + threadIdx.x; e < hi; e += 256) {
        int d = dst[e], s = src[e];
        int pos = atomicAdd(&cur[d >> BSH], 1);
        binned[pos] = (s << BSH) | (d & ((1 << BSH) - 1));
    }
}

__global__ __launch_bounds__(256) void k_bucket(const int* __restrict__ binned,
                                                const int* __restrict__ bstart,
                                                int* __restrict__ rowptr,
                                                int* __restrict__ deg,
                                                int* __restrict__ colidx, int N) {
    __shared__ int cnt[128], sc[128], cur[128];
    int k = blockIdx.x, t = threadIdx.x;
    int lo = bstart[k], hi = bstart[k + 1];
    if (t < 128) cnt[t] = 0;
    __syncthreads();
    for (int e = lo + t; e < hi; e += 256)
        atomicAdd(&cnt[binned[e] & 127], 1);
    __syncthreads();
    if (t < 128) sc[t] = cnt[t];
    __syncthreads();
    for (int off = 1; off < 128; off <<= 1) {
        int u = 0;
        if (t < 128 && t >= off) u = sc[t - off];
        __syncthreads();
        if (t < 128) sc[t] += u;
        __syncthreads();
    }
    if (t < 128) {
        int abs0 = lo + (sc[t] - cnt[t]);
        cur[t] = abs0;
        int gnode = (k << BSH) + t;
        if (gnode < N) { rowptr[gnode] = abs0; deg[gnode] = cnt[t]; }
    }
    __syncthreads();
    for (int e = lo + t; e < hi; e += 256) {
        int p = binned[e];
        int pos = atomicAdd(&cur[p & 127], 1);
        colidx[pos] = p >> BSH;
    }
}

// ---------------- fp32 -> fp16 prep for x ----------------
__global__ __launch_bounds__(256) void k_prep(const float* __restrict__ x,
                                              __half* __restrict__ xh, int n2) {
    int i = blockIdx.x * 256 + threadIdx.x;
    if (i < n2) {
        float2 v = ((const float2*)x)[i];
        ((__half2*)xh)[i] = __floats2half2_rn(v.x, v.y);
    }
}

// Broadcast neighbor row base address into VGPRs (divergent to the compiler)
__device__ __forceinline__ const __half* nbr_row(const __half* base, int sidx,
                                                 int j) {
    int idx = __builtin_amdgcn_ds_bpermute(j << 2, sidx);  // all lanes <- lane j
    return base + ((size_t)(unsigned)idx << 6);
}

// ---------------- Layers (R5: VGPR-addressed pipelined gathers) ----------------

// Layer 1: h1 = relu(mean([x|tau][nbrs]) @ W1l + [x|tau] @ W1r + b1l), stored fp16
__global__ __launch_bounds__(LAYER_BLOCK) void k_layer1(
    const float* __restrict__ x, const __half* __restrict__ xh,
    const float* __restrict__ tau,
    const int* __restrict__ rowptr, const int* __restrict__ deg,
    const int* __restrict__ colidx,
    const float* __restrict__ W1l, const float* __restrict__ b1l,
    const float* __restrict__ W1r, __half* __restrict__ h1, int N) {
    __shared__ float sW[65 * 64 * 2];
    for (int i = threadIdx.x; i < 65 * 64 * 2; i += LAYER_BLOCK)
        sW[i] = (i < 65 * 64) ? W1l[i] : W1r[i - 65 * 64];
    __syncthreads();
    const float* sWl = sW;
    const float* sWr = sW + 65 * 64;

    int lane = threadIdx.x & 63;
    int wave = blockIdx.x * WAVES_PER_BLOCK + (threadIdx.x >> 6);
    int nwaves = gridDim.x * WAVES_PER_BLOCK;

    float bl = b1l[lane];
    float wl_tau = sWl[64 * 64 + lane];
    float wr_tau = sWr[64 * 64 + lane];

    for (int node = wave; node < N; node += nwaves) {
        int start = rowptr[node];
        int d = deg[node];
        float s0 = 0.f, s1 = 0.f, s2 = 0.f, s3 = 0.f;
        float s4 = 0.f, s5 = 0.f, s6 = 0.f, s7 = 0.f;
        float sumtau = 0.f;
        for (int base = 0; base < d; base += 64) {
            int n = d - base;
            if (n > 64) n = 64;
            int sidx = 0;
            if (lane < n) {
                sidx = colidx[start + base + lane];
                sumtau += tau[sidx];
            }
            int jj = 0;
            for (; jj + 8 <= n; jj += 8) {
                const __half* p0 = nbr_row(xh, sidx, jj + 0);
                const __half* p1 = nbr_row(xh, sidx, jj + 1);
                const __half* p2 = nbr_row(xh, sidx, jj + 2);
                const __half* p3 = nbr_row(xh, sidx, jj + 3);
                const __half* p4 = nbr_row(xh, sidx, jj + 4);
                const __half* p5 = nbr_row(xh, sidx, jj + 5);
                const __half* p6 = nbr_row(xh, sidx, jj + 6);
                const __half* p7 = nbr_row(xh, sidx, jj + 7);
                s0 += __half2float(p0[lane]);
                s1 += __half2float(p1[lane]);
                s2 += __half2float(p2[lane]);
                s3 += __half2float(p3[lane]);
                s4 += __half2float(p4[lane]);
                s5 += __half2float(p5[lane]);
                s6 += __half2float(p6[lane]);
                s7 += __half2float(p7[lane]);
            }
            for (; jj < n; ++jj) {
                const __half* p = nbr_row(xh, sidx, jj);
                s0 += __half2float(p[lane]);
            }
        }
        float sum = ((s0 + s1) + (s2 + s3)) + ((s4 + s5) + (s6 + s7));
#pragma unroll
        for (int off = 32; off > 0; off >>= 1) sumtau += __shfl_down(sumtau, off, 64);
        sumtau = __shfl(sumtau, 0, 64);

        float inv = 1.f / fmaxf((float)d, 1.f);
        float mean = sum * inv;
        float mtau = sumtau * inv;
        float xi = x[(size_t)node * 64 + lane];
        float ti = tau[node];

        float acc = bl + mtau * wl_tau + ti * wr_tau;
#pragma unroll 8
        for (int k = 0; k < 64; ++k) {
            float mk = __shfl(mean, k, 64);
            float xk = __shfl(xi, k, 64);
            acc = fmaf(mk, sWl[k * 64 + lane], acc);
            acc = fmaf(xk, sWr[k * 64 + lane], acc);
        }
        h1[(size_t)node * 64 + lane] = __float2half(fmaxf(acc, 0.f));
    }
}

// Layer 2 + fc head: out = relu(mean(h1[nbrs]) @ W2l + h1 @ W2r + b2l) @ Wfc + bfc
__global__ __launch_bounds__(LAYER_BLOCK) void k_layer2(
    const __half* __restrict__ h1,
    const int* __restrict__ rowptr, const int* __restrict__ deg,
    const int* __restrict__ colidx,
    const float* __restrict__ W2l, const float* __restrict__ b2l,
    const float* __restrict__ W2r, const float* __restrict__ Wfc,
    const float* __restrict__ bfc, float* __restrict__ out, int N) {
    __shared__ float sW[64 * 64 * 2 + 64];
    for (int i = threadIdx.x; i < 64 * 64 * 2; i += LAYER_BLOCK)
        sW[i] = (i < 64 * 64) ? W2l[i] : W2r[i - 64 * 64];
    if (threadIdx.x < 64) sW[64 * 64 * 2 + threadIdx.x] = Wfc[threadIdx.x];
    __syncthreads();
    const float* sWl = sW;
    const float* sWr = sW + 64 * 64;
    const float* sWfc = sW + 64 * 64 * 2;

    int lane = threadIdx.x & 63;
    int wave = blockIdx.x * WAVES_PER_BLOCK + (threadIdx.x >> 6);
    int nwaves = gridDim.x * WAVES_PER_BLOCK;

    float bl = b2l[lane];
    float wfc = sWfc[lane];
    float b0 = bfc[0];

    for (int node = wave; node < N; node += nwaves) {
        int start = rowptr[node];
        int d = deg[node];
        float s0 = 0.f, s1 = 0.f, s2 = 0.f, s3 = 0.f;
        float s4 = 0.f, s5 = 0.f, s6 = 0.f, s7 = 0.f;
        for (int base = 0; base < d; base += 64) {
            int n = d - base;
            if (n > 64) n = 64;
            int sidx = 0;
            if (lane < n) sidx = colidx[start + base + lane];
            int jj = 0;
            for (; jj + 8 <= n; jj += 8) {
                const __half* p0 = nbr_row(h1, sidx, jj + 0);
                const __half* p1 = nbr_row(h1, sidx, jj + 1);
                const __half* p2 = nbr_row(h1, sidx, jj + 2);
                const __half* p3 = nbr_row(h1, sidx, jj + 3);
                const __half* p4 = nbr_row(h1, sidx, jj + 4);
                const __half* p5 = nbr_row(h1, sidx, jj + 5);
                const __half* p6 = nbr_row(h1, sidx, jj + 6);
                const __half* p7 = nbr_row(h1, sidx, jj + 7);
                s0 += __half2float(p0[lane]);
                s1 += __half2float(p1[lane]);
                s2 += __half2float(p2[lane]);
                s3 += __half2float(p3[lane]);
                s4 += __half2float(p4[lane]);
                s5 += __half2float(p5[lane]);
                s6 += __half2float(p6[lane]);
                s7 += __half2float(p7[lane]);
            }
            for (; jj < n; ++jj) {
                const __half* p = nbr_row(h1, sidx, jj);
                s0 += __half2float(p[lane]);
            }
        }
        float sum = ((s0 + s1) + (s2 + s3)) + ((s4 + s5) + (s6 + s7));
        float inv = 1.f / fmaxf((float)d, 1.f);
        float mean = sum * inv;
        float hi = __half2float(h1[(size_t)node * 64 + lane]);

        float acc = bl;
#pragma unroll 8
        for (int k = 0; k < 64; ++k) {
            float mk = __shfl(mean, k, 64);
            float hk = __shfl(hi, k, 64);
            acc = fmaf(mk, sWl[k * 64 + lane], acc);
            acc = fmaf(hk, sWr[k * 64 + lane], acc);
        }
        float h2 = fmaxf(acc, 0.f);
        float p = h2 * wfc;
#pragma unroll
        for (int off = 32; off > 0; off >>= 1) p += __shfl_down(p, off, 64);
        if (lane == 0) out[node] = p + b0;
    }
}

extern "C" void kernel_launch(void* const* d_in, const int* in_sizes, int n_in,
                              void* d_out, int out_size, void* d_ws, size_t ws_size,
                              hipStream_t stream) {
    const float* x   = (const float*)d_in[0];
    const int*   ei  = (const int*)d_in[1];
    const float* tau = (const float*)d_in[2];
    const float* W1l = (const float*)d_in[3];
    const float* b1l = (const float*)d_in[4];
    const float* W1r = (const float*)d_in[5];
    const float* W2l = (const float*)d_in[6];
    const float* b2l = (const float*)d_in[7];
    const float* W2r = (const float*)d_in[8];
    const float* Wfc = (const float*)d_in[9];
    const float* bfc = (const float*)d_in[10];
    float* out = (float*)d_out;

    const int N = in_sizes[0] / 64;   // 100000
    const int E = in_sizes[1] / 2;    // 3200000
    const int* src = ei;
    const int* dst = ei + E;

    char* w = (char*)d_ws;
    auto take = [&](size_t b) { char* p = w; w += (b + 255) & ~(size_t)255; return p; };
    int*    histT  = (int*)take((size_t)NBKT * NBLK * 4);
    int*    btot   = (int*)take((size_t)NBKT * 4);
    int*    bstart = (int*)take((size_t)(NBKT + 1) * 4);
    int*    binned = (int*)take((size_t)E * 4);
    int*    rowptr = (int*)take((size_t)N * 4);
    int*    deg    = (int*)take((size_t)N * 4);
    int*    colidx = (int*)take((size_t)E * 4);
    __half* xh     = (__half*)take((size_t)N * 64 * 2);   // 12.8 MB
    __half* h1     = (__half*)take((size_t)N * 64 * 2);   // 12.8 MB

    int n2 = N * 32;  // N*64/2 half2 elements

    k_hist   <<<NBLK, 256, 0, stream>>>(dst, histT, E);
    k_scanblk<<<NBKT, NBLK, 0, stream>>>(histT, btot);
    k_scanbkt<<<1, 1024, 0, stream>>>(btot, bstart);
    k_scatter<<<NBLK, 256, 0, stream>>>(src, dst, histT, bstart, binned, E);
    k_bucket <<<NBKT, 256, 0, stream>>>(binned, bstart, rowptr, deg, colidx, N);
    k_prep   <<<(n2 + 255) / 256, 256, 0, stream>>>(x, xh, n2);
    k_layer1 <<<LAYER_GRID, LAYER_BLOCK, 0, stream>>>(x, xh, tau, rowptr, deg, colidx,
                                                      W1l, b1l, W1r, h1, N);
    k_layer2 <<<LAYER_GRID, LAYER_BLOCK, 0, stream>>>(h1, rowptr, deg, colidx,
                                                      W2l, b2l, W2r, Wfc, bfc, out, N);
}

// Round 6
// 358.744 us; speedup vs baseline: 1.8146x; 1.8146x over previous
//
#include <hip/hip_runtime.h>
#include <hip/hip_bf16.h>
#include <hip/hip_fp16.h>

// GQNN: 2-layer GraphSAGE (mean aggr) + fc head. N=100k, E=3.2M, d=64/65.
// R6: split layers into aggregate (gather-only) + fp16 MFMA GEMM kernels.
// R2/R4/R5 evidence: layer time pinned at ~260us regardless of gather dtype/
// unroll/addressing => bottleneck is the fused dense GEMV's LDS-pipe traffic
// (128 ds_read + 128 shfl per node ~= 273us/CU at 5.8cyc/op). MFMA GEMM with
// pre-swizzled B fragments does the dense part on the matrix pipe with zero
// LDS. Build kernels unchanged from R2.

#define WAVES_PER_BLOCK 16
#define LAYER_BLOCK (WAVES_PER_BLOCK * 64)
#define LAYER_GRID 512

#define BSH 7                    // bucket shift: 128 nodes per bucket
#define NBKT 782                 // ceil(100000 / 128)
#define NBLK 256                 // binning blocks

typedef _Float16 half8 __attribute__((ext_vector_type(8)));
typedef float floatx4 __attribute__((ext_vector_type(4)));

// ---------------- CSR build (unchanged from R2) ----------------

__global__ __launch_bounds__(256) void k_hist(const int* __restrict__ dst,
                                              int* __restrict__ histT, int E) {
    __shared__ int h[NBKT];
    for (int i = threadIdx.x; i < NBKT; i += 256) h[i] = 0;
    __syncthreads();
    int per = (E + NBLK - 1) / NBLK;
    int lo = blockIdx.x * per;
    int hi = lo + per; if (hi > E) hi = E;
    for (int e = lo + threadIdx.x; e < hi; e += 256)
        atomicAdd(&h[dst[e] >> BSH], 1);
    __syncthreads();
    for (int k = threadIdx.x; k < NBKT; k += 256)
        histT[k * NBLK + blockIdx.x] = h[k];
}

__global__ __launch_bounds__(NBLK) void k_scanblk(int* __restrict__ histT,
                                                  int* __restrict__ btot) {
    __shared__ int s[NBLK];
    int k = blockIdx.x, t = threadIdx.x;
    int v = histT[k * NBLK + t];
    s[t] = v;
    __syncthreads();
    for (int off = 1; off < NBLK; off <<= 1) {
        int u = (t >= off) ? s[t - off] : 0;
        __syncthreads();
        s[t] += u;
        __syncthreads();
    }
    histT[k * NBLK + t] = s[t] - v;
    if (t == NBLK - 1) btot[k] = s[t];
}

__global__ __launch_bounds__(1024) void k_scanbkt(const int* __restrict__ btot,
                                                  int* __restrict__ bstart) {
    __shared__ int s[1024];
    int t = threadIdx.x;
    int v = (t < NBKT) ? btot[t] : 0;
    s[t] = v;
    __syncthreads();
    for (int off = 1; off < 1024; off <<= 1) {
        int u = (t >= off) ? s[t - off] : 0;
        __syncthreads();
        s[t] += u;
        __syncthreads();
    }
    if (t < NBKT) bstart[t] = s[t] - v;
    if (t == NBKT - 1) bstart[NBKT] = s[t];
}

__global__ __launch_bounds__(256) void k_scatter(const int* __restrict__ src,
                                                 const int* __restrict__ dst,
                                                 const int* __restrict__ histT,
                                                 const int* __restrict__ bstart,
                                                 int* __restrict__ binned, int E) {
    __shared__ int cur[NBKT];
    int b = blockIdx.x;
    for (int k = threadIdx.x; k < NBKT; k += 256)
        cur[k] = bstart[k] + histT[k * NBLK + b];
    __syncthreads();
    int per = (E + NBLK - 1) / NBLK;
    int lo = b * per;
    int hi = lo + per; if (hi > E) hi = E;
    for (int e = lo + threadIdx.x; e < hi; e += 256) {
        int d = dst[e], s = src[e];
        int pos = atomicAdd(&cur[d >> BSH], 1);
        binned[pos] = (s << BSH) | (d & ((1 << BSH) - 1));
    }
}

__global__ __launch_bounds__(256) void k_bucket(const int* __restrict__ binned,
                                                const int* __restrict__ bstart,
                                                int* __restrict__ rowptr,
                                                int* __restrict__ deg,
                                                int* __restrict__ colidx, int N) {
    __shared__ int cnt[128], sc[128], cur[128];
    int k = blockIdx.x, t = threadIdx.x;
    int lo = bstart[k], hi = bstart[k + 1];
    if (t < 128) cnt[t] = 0;
    __syncthreads();
    for (int e = lo + t; e < hi; e += 256)
        atomicAdd(&cnt[binned[e] & 127], 1);
    __syncthreads();
    if (t < 128) sc[t] = cnt[t];
    __syncthreads();
    for (int off = 1; off < 128; off <<= 1) {
        int u = 0;
        if (t < 128 && t >= off) u = sc[t - off];
        __syncthreads();
        if (t < 128) sc[t] += u;
        __syncthreads();
    }
    if (t < 128) {
        int abs0 = lo + (sc[t] - cnt[t]);
        cur[t] = abs0;
        int gnode = (k << BSH) + t;
        if (gnode < N) { rowptr[gnode] = abs0; deg[gnode] = cnt[t]; }
    }
    __syncthreads();
    for (int e = lo + t; e < hi; e += 256) {
        int p = binned[e];
        int pos = atomicAdd(&cur[p & 127], 1);
        colidx[pos] = p >> BSH;
    }
}

// ---------------- fp32 -> fp16 prep for x ----------------
__global__ __launch_bounds__(256) void k_prep(const float* __restrict__ x,
                                              __half* __restrict__ xh, int n2) {
    int i = blockIdx.x * 256 + threadIdx.x;
    if (i < n2) {
        float2 v = ((const float2*)x)[i];
        ((__half2*)xh)[i] = __floats2half2_rn(v.x, v.y);
    }
}

// ---------------- W -> fp16 B-fragment swizzle ----------------
// B frag for mfma_f32_16x16x32_f16: lane = n + 16*quad holds B[k=quad*8+j][n].
// wbuf layout: [(kstep*4 + ntile)*64 + lane] * 8 + j.
// Layer1: Wcat1[160][64] = [W1l(65) ; W1r(65) ; 0(30)], 5 ksteps.
// Layer2: Wcat2[128][64] = [W2l(64) ; W2r(64)], 4 ksteps.
__global__ __launch_bounds__(256) void k_prepw(
    const float* __restrict__ W1l, const float* __restrict__ W1r,
    const float* __restrict__ W2l, const float* __restrict__ W2r,
    __half* __restrict__ wbuf1, __half* __restrict__ wbuf2) {
    int idx = blockIdx.x * 256 + threadIdx.x;
    if (idx < 1280) {
        int lane = idx & 63;
        int nt = (idx >> 6) & 3;
        int kstep = idx >> 8;
        int col = nt * 16 + (lane & 15);
        int kbase = kstep * 32 + (lane >> 4) * 8;
#pragma unroll
        for (int j = 0; j < 8; ++j) {
            int k = kbase + j;
            float v = (k < 65) ? W1l[k * 64 + col]
                               : ((k < 130) ? W1r[(k - 65) * 64 + col] : 0.f);
            wbuf1[(size_t)idx * 8 + j] = __float2half(v);
        }
    } else if (idx < 1280 + 1024) {
        int i2 = idx - 1280;
        int lane = i2 & 63;
        int nt = (i2 >> 6) & 3;
        int kstep = i2 >> 8;
        int col = nt * 16 + (lane & 15);
        int kbase = kstep * 32 + (lane >> 4) * 8;
#pragma unroll
        for (int j = 0; j < 8; ++j) {
            int k = kbase + j;
            float v = (k < 64) ? W2l[k * 64 + col] : W2r[(k - 64) * 64 + col];
            wbuf2[(size_t)i2 * 8 + j] = __float2half(v);
        }
    }
}

// ---------------- Aggregation kernels (gather + mean only) ----------------

// z1[node] (160 fp16) = [mean_x(64) | mean_tau | x_self(64) | tau | 0 x30]
__global__ __launch_bounds__(LAYER_BLOCK) void k_aggr1(
    const __half* __restrict__ xh, const float* __restrict__ tau,
    const int* __restrict__ rowptr, const int* __restrict__ deg,
    const int* __restrict__ colidx, __half* __restrict__ z1, int N) {
    int lane = threadIdx.x & 63;
    int wave = blockIdx.x * WAVES_PER_BLOCK + (threadIdx.x >> 6);
    int nwaves = gridDim.x * WAVES_PER_BLOCK;

    for (int node = wave; node < N; node += nwaves) {
        int start = rowptr[node];
        int d = deg[node];
        float s0 = 0.f, s1 = 0.f, s2 = 0.f, s3 = 0.f;
        float s4 = 0.f, s5 = 0.f, s6 = 0.f, s7 = 0.f;
        float sumtau = 0.f;
        for (int base = 0; base < d; base += 64) {
            int n = d - base;
            if (n > 64) n = 64;
            int sidx = 0;
            if (lane < n) {
                sidx = colidx[start + base + lane];
                sumtau += tau[sidx];
            }
            int jj = 0;
            for (; jj + 8 <= n; jj += 8) {
                int a0 = __shfl(sidx, jj, 64);
                int a1 = __shfl(sidx, jj + 1, 64);
                int a2 = __shfl(sidx, jj + 2, 64);
                int a3 = __shfl(sidx, jj + 3, 64);
                int a4 = __shfl(sidx, jj + 4, 64);
                int a5 = __shfl(sidx, jj + 5, 64);
                int a6 = __shfl(sidx, jj + 6, 64);
                int a7 = __shfl(sidx, jj + 7, 64);
                s0 += __half2float(xh[(size_t)a0 * 64 + lane]);
                s1 += __half2float(xh[(size_t)a1 * 64 + lane]);
                s2 += __half2float(xh[(size_t)a2 * 64 + lane]);
                s3 += __half2float(xh[(size_t)a3 * 64 + lane]);
                s4 += __half2float(xh[(size_t)a4 * 64 + lane]);
                s5 += __half2float(xh[(size_t)a5 * 64 + lane]);
                s6 += __half2float(xh[(size_t)a6 * 64 + lane]);
                s7 += __half2float(xh[(size_t)a7 * 64 + lane]);
            }
            for (; jj < n; ++jj) {
                int a = __shfl(sidx, jj, 64);
                s0 += __half2float(xh[(size_t)a * 64 + lane]);
            }
        }
        float sum = ((s0 + s1) + (s2 + s3)) + ((s4 + s5) + (s6 + s7));
#pragma unroll
        for (int off = 32; off > 0; off >>= 1) sumtau += __shfl_down(sumtau, off, 64);
        sumtau = __shfl(sumtau, 0, 64);

        float inv = 1.f / fmaxf((float)d, 1.f);
        __half* zrow = z1 + (size_t)node * 160;
        zrow[lane] = __float2half(sum * inv);
        zrow[65 + lane] = xh[(size_t)node * 64 + lane];
        if (lane == 0) {
            zrow[64] = __float2half(sumtau * inv);
            zrow[129] = __float2half(tau[node]);
        }
        if (lane < 30) zrow[130 + lane] = __float2half(0.f);
    }
}

// z2[node] (128 fp16) = [mean_h1(64) | h1_self(64)]
__global__ __launch_bounds__(LAYER_BLOCK) void k_aggr2(
    const __half* __restrict__ h1,
    const int* __restrict__ rowptr, const int* __restrict__ deg,
    const int* __restrict__ colidx, __half* __restrict__ z2, int N) {
    int lane = threadIdx.x & 63;
    int wave = blockIdx.x * WAVES_PER_BLOCK + (threadIdx.x >> 6);
    int nwaves = gridDim.x * WAVES_PER_BLOCK;

    for (int node = wave; node < N; node += nwaves) {
        int start = rowptr[node];
        int d = deg[node];
        float s0 = 0.f, s1 = 0.f, s2 = 0.f, s3 = 0.f;
        float s4 = 0.f, s5 = 0.f, s6 = 0.f, s7 = 0.f;
        for (int base = 0; base < d; base += 64) {
            int n = d - base;
            if (n > 64) n = 64;
            int sidx = 0;
            if (lane < n) sidx = colidx[start + base + lane];
            int jj = 0;
            for (; jj + 8 <= n; jj += 8) {
                int a0 = __shfl(sidx, jj, 64);
                int a1 = __shfl(sidx, jj + 1, 64);
                int a2 = __shfl(sidx, jj + 2, 64);
                int a3 = __shfl(sidx, jj + 3, 64);
                int a4 = __shfl(sidx, jj + 4, 64);
                int a5 = __shfl(sidx, jj + 5, 64);
                int a6 = __shfl(sidx, jj + 6, 64);
                int a7 = __shfl(sidx, jj + 7, 64);
                s0 += __half2float(h1[(size_t)a0 * 64 + lane]);
                s1 += __half2float(h1[(size_t)a1 * 64 + lane]);
                s2 += __half2float(h1[(size_t)a2 * 64 + lane]);
                s3 += __half2float(h1[(size_t)a3 * 64 + lane]);
                s4 += __half2float(h1[(size_t)a4 * 64 + lane]);
                s5 += __half2float(h1[(size_t)a5 * 64 + lane]);
                s6 += __half2float(h1[(size_t)a6 * 64 + lane]);
                s7 += __half2float(h1[(size_t)a7 * 64 + lane]);
            }
            for (; jj < n; ++jj) {
                int a = __shfl(sidx, jj, 64);
                s0 += __half2float(h1[(size_t)a * 64 + lane]);
            }
        }
        float sum = ((s0 + s1) + (s2 + s3)) + ((s4 + s5) + (s6 + s7));
        float inv = 1.f / fmaxf((float)d, 1.f);
        __half* zrow = z2 + (size_t)node * 128;
        zrow[lane] = __float2half(sum * inv);
        zrow[64 + lane] = h1[(size_t)node * 64 + lane];
    }
}

// ---------------- MFMA GEMM kernels ----------------
// A frag: lane = m + 16*quad holds A[m][quad*8 + j] (j=0..7), contiguous 16B.
// C frag: col = lane&15, row = (lane>>4)*4 + reg.
// M = 100000 = 6250 exact 16-row tiles; one tile per wave, 4 waves/block.

// h1 = relu(z1 @ Wcat1 + b1l), fp16 out
__global__ __launch_bounds__(256) void k_gemm1(
    const __half* __restrict__ z1, const __half* __restrict__ wbuf1,
    const float* __restrict__ b1l, __half* __restrict__ h1, int ntiles) {
    int tile = blockIdx.x * 4 + (threadIdx.x >> 6);
    if (tile >= ntiles) return;
    int lane = threadIdx.x & 63;
    int sub = lane & 15;
    int quad = lane >> 4;

    floatx4 acc0 = {0.f, 0.f, 0.f, 0.f};
    floatx4 acc1 = {0.f, 0.f, 0.f, 0.f};
    floatx4 acc2 = {0.f, 0.f, 0.f, 0.f};
    floatx4 acc3 = {0.f, 0.f, 0.f, 0.f};

    const _Float16* zrow = (const _Float16*)z1 + (size_t)(tile * 16 + sub) * 160 + quad * 8;
    const _Float16* wb = (const _Float16*)wbuf1 + (size_t)lane * 8;
#pragma unroll
    for (int ks = 0; ks < 5; ++ks) {
        half8 a = *(const half8*)(zrow + ks * 32);
        half8 b0 = *(const half8*)(wb + (size_t)(ks * 4 + 0) * 512);
        half8 b1 = *(const half8*)(wb + (size_t)(ks * 4 + 1) * 512);
        half8 b2 = *(const half8*)(wb + (size_t)(ks * 4 + 2) * 512);
        half8 b3 = *(const half8*)(wb + (size_t)(ks * 4 + 3) * 512);
        acc0 = __builtin_amdgcn_mfma_f32_16x16x32_f16(a, b0, acc0, 0, 0, 0);
        acc1 = __builtin_amdgcn_mfma_f32_16x16x32_f16(a, b1, acc1, 0, 0, 0);
        acc2 = __builtin_amdgcn_mfma_f32_16x16x32_f16(a, b2, acc2, 0, 0, 0);
        acc3 = __builtin_amdgcn_mfma_f32_16x16x32_f16(a, b3, acc3, 0, 0, 0);
    }
    float bv0 = b1l[sub], bv1 = b1l[16 + sub], bv2 = b1l[32 + sub], bv3 = b1l[48 + sub];
#pragma unroll
    for (int reg = 0; reg < 4; ++reg) {
        int row = quad * 4 + reg;
        __half* orow = h1 + (size_t)(tile * 16 + row) * 64;
        orow[sub]      = __float2half(fmaxf(acc0[reg] + bv0, 0.f));
        orow[16 + sub] = __float2half(fmaxf(acc1[reg] + bv1, 0.f));
        orow[32 + sub] = __float2half(fmaxf(acc2[reg] + bv2, 0.f));
        orow[48 + sub] = __float2half(fmaxf(acc3[reg] + bv3, 0.f));
    }
}

// out = relu(z2 @ Wcat2 + b2l) @ Wfc + bfc  (fc fused into epilogue)
__global__ __launch_bounds__(256) void k_gemm2(
    const __half* __restrict__ z2, const __half* __restrict__ wbuf2,
    const float* __restrict__ b2l, const float* __restrict__ Wfc,
    const float* __restrict__ bfc, float* __restrict__ out, int ntiles) {
    int tile = blockIdx.x * 4 + (threadIdx.x >> 6);
    if (tile >= ntiles) return;
    int lane = threadIdx.x & 63;
    int sub = lane & 15;
    int quad = lane >> 4;

    floatx4 acc0 = {0.f, 0.f, 0.f, 0.f};
    floatx4 acc1 = {0.f, 0.f, 0.f, 0.f};
    floatx4 acc2 = {0.f, 0.f, 0.f, 0.f};
    floatx4 acc3 = {0.f, 0.f, 0.f, 0.f};

    const _Float16* zrow = (const _Float16*)z2 + (size_t)(tile * 16 + sub) * 128 + quad * 8;
    const _Float16* wb = (const _Float16*)wbuf2 + (size_t)lane * 8;
#pragma unroll
    for (int ks = 0; ks < 4; ++ks) {
        half8 a = *(const half8*)(zrow + ks * 32);
        half8 b0 = *(const half8*)(wb + (size_t)(ks * 4 + 0) * 512);
        half8 b1 = *(const half8*)(wb + (size_t)(ks * 4 + 1) * 512);
        half8 b2 = *(const half8*)(wb + (size_t)(ks * 4 + 2) * 512);
        half8 b3 = *(const half8*)(wb + (size_t)(ks * 4 + 3) * 512);
        acc0 = __builtin_amdgcn_mfma_f32_16x16x32_f16(a, b0, acc0, 0, 0, 0);
        acc1 = __builtin_amdgcn_mfma_f32_16x16x32_f16(a, b1, acc1, 0, 0, 0);
        acc2 = __builtin_amdgcn_mfma_f32_16x16x32_f16(a, b2, acc2, 0, 0, 0);
        acc3 = __builtin_amdgcn_mfma_f32_16x16x32_f16(a, b3, acc3, 0, 0, 0);
    }
    float bb0 = b2l[sub], bb1 = b2l[16 + sub], bb2 = b2l[32 + sub], bb3 = b2l[48 + sub];
    float wv0 = Wfc[sub], wv1 = Wfc[16 + sub], wv2 = Wfc[32 + sub], wv3 = Wfc[48 + sub];
    float p[4];
#pragma unroll
    for (int reg = 0; reg < 4; ++reg) {
        p[reg] = fmaxf(acc0[reg] + bb0, 0.f) * wv0
               + fmaxf(acc1[reg] + bb1, 0.f) * wv1
               + fmaxf(acc2[reg] + bb2, 0.f) * wv2
               + fmaxf(acc3[reg] + bb3, 0.f) * wv3;
    }
#pragma unroll
    for (int m = 1; m <= 8; m <<= 1) {
#pragma unroll
        for (int reg = 0; reg < 4; ++reg) p[reg] += __shfl_xor(p[reg], m, 64);
    }
    if (sub == 0) {
        float b0 = bfc[0];
#pragma unroll
        for (int reg = 0; reg < 4; ++reg)
            out[tile * 16 + quad * 4 + reg] = p[reg] + b0;
    }
}

extern "C" void kernel_launch(void* const* d_in, const int* in_sizes, int n_in,
                              void* d_out, int out_size, void* d_ws, size_t ws_size,
                              hipStream_t stream) {
    const float* x   = (const float*)d_in[0];
    const int*   ei  = (const int*)d_in[1];
    const float* tau = (const float*)d_in[2];
    const float* W1l = (const float*)d_in[3];
    const float* b1l = (const float*)d_in[4];
    const float* W1r = (const float*)d_in[5];
    const float* W2l = (const float*)d_in[6];
    const float* b2l = (const float*)d_in[7];
    const float* W2r = (const float*)d_in[8];
    const float* Wfc = (const float*)d_in[9];
    const float* bfc = (const float*)d_in[10];
    float* out = (float*)d_out;

    const int N = in_sizes[0] / 64;   // 100000
    const int E = in_sizes[1] / 2;    // 3200000
    const int* src = ei;
    const int* dst = ei + E;

    char* w = (char*)d_ws;
    auto take = [&](size_t b) { char* p = w; w += (b + 255) & ~(size_t)255; return p; };
    int*    histT  = (int*)take((size_t)NBKT * NBLK * 4);
    int*    btot   = (int*)take((size_t)NBKT * 4);
    int*    bstart = (int*)take((size_t)(NBKT + 1) * 4);
    int*    binned = (int*)take((size_t)E * 4);
    int*    rowptr = (int*)take((size_t)N * 4);
    int*    deg    = (int*)take((size_t)N * 4);
    int*    colidx = (int*)take((size_t)E * 4);
    __half* xh     = (__half*)take((size_t)N * 64 * 2);    // 12.8 MB
    __half* h1     = (__half*)take((size_t)N * 64 * 2);    // 12.8 MB
    __half* z1     = (__half*)take((size_t)N * 160 * 2);   // 32 MB
    __half* z2     = (__half*)take((size_t)N * 128 * 2);   // 25.6 MB
    __half* wbuf1  = (__half*)take(1280 * 8 * 2);          // 20 KB
    __half* wbuf2  = (__half*)take(1024 * 8 * 2);          // 16 KB

    int n2 = N * 32;                  // half2 elements for prep
    int ntiles = N / 16;              // 6250 (exact)
    int gblocks = (ntiles + 3) / 4;   // 1563

    k_hist   <<<NBLK, 256, 0, stream>>>(dst, histT, E);
    k_scanblk<<<NBKT, NBLK, 0, stream>>>(histT, btot);
    k_scanbkt<<<1, 1024, 0, stream>>>(btot, bstart);
    k_scatter<<<NBLK, 256, 0, stream>>>(src, dst, histT, bstart, binned, E);
    k_bucket <<<NBKT, 256, 0, stream>>>(binned, bstart, rowptr, deg, colidx, N);
    k_prep   <<<(n2 + 255) / 256, 256, 0, stream>>>(x, xh, n2);
    k_prepw  <<<9, 256, 0, stream>>>(W1l, W1r, W2l, W2r, wbuf1, wbuf2);
    k_aggr1  <<<LAYER_GRID, LAYER_BLOCK, 0, stream>>>(xh, tau, rowptr, deg, colidx, z1, N);
    k_gemm1  <<<gblocks, 256, 0, stream>>>(z1, wbuf1, b1l, h1, ntiles);
    k_aggr2  <<<LAYER_GRID, LAYER_BLOCK, 0, stream>>>(h1, rowptr, deg, colidx, z2, N);
    k_gemm2  <<<gblocks, 256, 0, stream>>>(z2, wbuf2, b2l, Wfc, bfc, out, ntiles);
}

// Round 7
// 308.946 us; speedup vs baseline: 2.1071x; 1.1612x over previous
//
#include <hip/hip_runtime.h>
#include <hip/hip_bf16.h>
#include <hip/hip_fp16.h>

// GQNN: 2-layer GraphSAGE (mean aggr) + fc head. N=100k, E=3.2M, d=64/65.
// R7: (a) packed-pair gathers in aggr kernels: lanes 0-31 take even neighbor,
// 32-63 odd; each lane loads half2 (2 cols) => 1 load + 1 bpermute per 2
// neighbors (R6: 2 loads + 2 shfl) — aggr is issue-bound (R6: 83us matches
// ~6.5cy/nbr issue model). (b) gemms read self-rows directly from xh/h1;
// aggr only materializes the mean => -51MB z traffic. Build from R2.

#define WAVES_PER_BLOCK 16
#define LAYER_BLOCK (WAVES_PER_BLOCK * 64)
#define LAYER_GRID 512

#define BSH 7                    // bucket shift: 128 nodes per bucket
#define NBKT 782                 // ceil(100000 / 128)
#define NBLK 256                 // binning blocks

typedef _Float16 half8 __attribute__((ext_vector_type(8)));
typedef float floatx4 __attribute__((ext_vector_type(4)));

// ---------------- CSR build (unchanged from R2) ----------------

__global__ __launch_bounds__(256) void k_hist(const int* __restrict__ dst,
                                              int* __restrict__ histT, int E) {
    __shared__ int h[NBKT];
    for (int i = threadIdx.x; i < NBKT; i += 256) h[i] = 0;
    __syncthreads();
    int per = (E + NBLK - 1) / NBLK;
    int lo = blockIdx.x * per;
    int hi = lo + per; if (hi > E) hi = E;
    for (int e = lo + threadIdx.x; e < hi; e += 256)
        atomicAdd(&h[dst[e] >> BSH], 1);
    __syncthreads();
    for (int k = threadIdx.x; k < NBKT; k += 256)
        histT[k * NBLK + blockIdx.x] = h[k];
}

__global__ __launch_bounds__(NBLK) void k_scanblk(int* __restrict__ histT,
                                                  int* __restrict__ btot) {
    __shared__ int s[NBLK];
    int k = blockIdx.x, t = threadIdx.x;
    int v = histT[k * NBLK + t];
    s[t] = v;
    __syncthreads();
    for (int off = 1; off < NBLK; off <<= 1) {
        int u = (t >= off) ? s[t - off] : 0;
        __syncthreads();
        s[t] += u;
        __syncthreads();
    }
    histT[k * NBLK + t] = s[t] - v;
    if (t == NBLK - 1) btot[k] = s[t];
}

__global__ __launch_bounds__(1024) void k_scanbkt(const int* __restrict__ btot,
                                                  int* __restrict__ bstart) {
    __shared__ int s[1024];
    int t = threadIdx.x;
    int v = (t < NBKT) ? btot[t] : 0;
    s[t] = v;
    __syncthreads();
    for (int off = 1; off < 1024; off <<= 1) {
        int u = (t >= off) ? s[t - off] : 0;
        __syncthreads();
        s[t] += u;
        __syncthreads();
    }
    if (t < NBKT) bstart[t] = s[t] - v;
    if (t == NBKT - 1) bstart[NBKT] = s[t];
}

__global__ __launch_bounds__(256) void k_scatter(const int* __restrict__ src,
                                                 const int* __restrict__ dst,
                                                 const int* __restrict__ histT,
                                                 const int* __restrict__ bstart,
                                                 int* __restrict__ binned, int E) {
    __shared__ int cur[NBKT];
    int b = blockIdx.x;
    for (int k = threadIdx.x; k < NBKT; k += 256)
        cur[k] = bstart[k] + histT[k * NBLK + b];
    __syncthreads();
    int per = (E + NBLK - 1) / NBLK;
    int lo = b * per;
    int hi = lo + per; if (hi > E) hi = E;
    for (int e = lo + threadIdx.x; e < hi; e += 256) {
        int d = dst[e], s = src[e];
        int pos = atomicAdd(&cur[d >> BSH], 1);
        binned[pos] = (s << BSH) | (d & ((1 << BSH) - 1));
    }
}

__global__ __launch_bounds__(256) void k_bucket(const int* __restrict__ binned,
                                                const int* __restrict__ bstart,
                                                int* __restrict__ rowptr,
                                                int* __restrict__ deg,
                                                int* __restrict__ colidx, int N) {
    __shared__ int cnt[128], sc[128], cur[128];
    int k = blockIdx.x, t = threadIdx.x;
    int lo = bstart[k], hi = bstart[k + 1];
    if (t < 128) cnt[t] = 0;
    __syncthreads();
    for (int e = lo + t; e < hi; e += 256)
        atomicAdd(&cnt[binned[e] & 127], 1);
    __syncthreads();
    if (t < 128) sc[t] = cnt[t];
    __syncthreads();
    for (int off = 1; off < 128; off <<= 1) {
        int u = 0;
        if (t < 128 && t >= off) u = sc[t - off];
        __syncthreads();
        if (t < 128) sc[t] += u;
        __syncthreads();
    }
    if (t < 128) {
        int abs0 = lo + (sc[t] - cnt[t]);
        cur[t] = abs0;
        int gnode = (k << BSH) + t;
        if (gnode < N) { rowptr[gnode] = abs0; deg[gnode] = cnt[t]; }
    }
    __syncthreads();
    for (int e = lo + t; e < hi; e += 256) {
        int p = binned[e];
        int pos = atomicAdd(&cur[p & 127], 1);
        colidx[pos] = p >> BSH;
    }
}

// ---------------- fp32 -> fp16 prep for x ----------------
__global__ __launch_bounds__(256) void k_prep(const float* __restrict__ x,
                                              __half* __restrict__ xh, int n2) {
    int i = blockIdx.x * 256 + threadIdx.x;
    if (i < n2) {
        float2 v = ((const float2*)x)[i];
        ((__half2*)xh)[i] = __floats2half2_rn(v.x, v.y);
    }
}

// ---------------- W -> fp16 B-fragment swizzle ----------------
// B frag for mfma_f32_16x16x32_f16: lane = n + 16*quad holds B[k=quad*8+j][n].
// wbuf layout: [(kstep*4 + ntile)*64 + lane] * 8 + j.
// Layer1 Wcat1[160][64]: rows 0-63 = W1l[0:64]; 64-127 = W1r[0:64];
//   128 = W1l[64] (tau row); 129 = W1r[64]; 130-159 = 0.   (5 ksteps)
// Layer2 Wcat2[128][64]: rows 0-63 = W2l; 64-127 = W2r.     (4 ksteps)
__global__ __launch_bounds__(256) void k_prepw(
    const float* __restrict__ W1l, const float* __restrict__ W1r,
    const float* __restrict__ W2l, const float* __restrict__ W2r,
    __half* __restrict__ wbuf1, __half* __restrict__ wbuf2) {
    int idx = blockIdx.x * 256 + threadIdx.x;
    if (idx < 1280) {
        int lane = idx & 63;
        int nt = (idx >> 6) & 3;
        int kstep = idx >> 8;
        int col = nt * 16 + (lane & 15);
        int kbase = kstep * 32 + (lane >> 4) * 8;
#pragma unroll
        for (int j = 0; j < 8; ++j) {
            int k = kbase + j;
            float v;
            if (k < 64)       v = W1l[k * 64 + col];
            else if (k < 128) v = W1r[(k - 64) * 64 + col];
            else if (k == 128) v = W1l[64 * 64 + col];
            else if (k == 129) v = W1r[64 * 64 + col];
            else v = 0.f;
            wbuf1[(size_t)idx * 8 + j] = __float2half(v);
        }
    } else if (idx < 1280 + 1024) {
        int i2 = idx - 1280;
        int lane = i2 & 63;
        int nt = (i2 >> 6) & 3;
        int kstep = i2 >> 8;
        int col = nt * 16 + (lane & 15);
        int kbase = kstep * 32 + (lane >> 4) * 8;
#pragma unroll
        for (int j = 0; j < 8; ++j) {
            int k = kbase + j;
            float v = (k < 64) ? W2l[k * 64 + col] : W2r[(k - 64) * 64 + col];
            wbuf2[(size_t)i2 * 8 + j] = __float2half(v);
        }
    }
}

// ---------------- Aggregation (packed pair gathers, mean only) ----------------
// Lane role: half = lane>>5 (0: even neighbor, 1: odd); c = lane&31 covers
// cols {2c, 2c+1} via a single half2 load. One bpermute serves both halves.

__device__ __forceinline__ int pair_idx(int sidx, int j2, int half) {
    // broadcast colidx from lane (j2 + half) to all lanes
    return __builtin_amdgcn_ds_bpermute(((j2 + half) << 2), sidx);
}

// zm1[node][64] = mean_x (fp16); mt1[node] = mean_tau (fp16)
__global__ __launch_bounds__(LAYER_BLOCK) void k_aggr1(
    const __half* __restrict__ xh, const float* __restrict__ tau,
    const int* __restrict__ rowptr, const int* __restrict__ deg,
    const int* __restrict__ colidx,
    __half* __restrict__ zm1, __half* __restrict__ mt1, int N) {
    int lane = threadIdx.x & 63;
    int half = lane >> 5;
    int c2 = (lane & 31) << 1;
    int wave = blockIdx.x * WAVES_PER_BLOCK + (threadIdx.x >> 6);
    int nwaves = gridDim.x * WAVES_PER_BLOCK;

    for (int node = wave; node < N; node += nwaves) {
        int start = rowptr[node];
        int d = deg[node];
        float2 A0 = {0.f, 0.f}, A1 = {0.f, 0.f}, A2 = {0.f, 0.f}, A3 = {0.f, 0.f};
        float sumtau = 0.f;
        for (int base = 0; base < d; base += 64) {
            int n = d - base;
            if (n > 64) n = 64;
            int sidx = 0;
            if (lane < n) {
                sidx = colidx[start + base + lane];
                sumtau += tau[sidx];
            }
            int npair = n >> 1;
            int j = 0;
            for (; j + 4 <= npair; j += 4) {
                int i0 = pair_idx(sidx, (j + 0) << 1, half);
                int i1 = pair_idx(sidx, (j + 1) << 1, half);
                int i2 = pair_idx(sidx, (j + 2) << 1, half);
                int i3 = pair_idx(sidx, (j + 3) << 1, half);
                float2 v0 = __half22float2(*(const __half2*)(xh + ((size_t)(unsigned)i0 << 6) + c2));
                float2 v1 = __half22float2(*(const __half2*)(xh + ((size_t)(unsigned)i1 << 6) + c2));
                float2 v2 = __half22float2(*(const __half2*)(xh + ((size_t)(unsigned)i2 << 6) + c2));
                float2 v3 = __half22float2(*(const __half2*)(xh + ((size_t)(unsigned)i3 << 6) + c2));
                A0.x += v0.x; A0.y += v0.y;
                A1.x += v1.x; A1.y += v1.y;
                A2.x += v2.x; A2.y += v2.y;
                A3.x += v3.x; A3.y += v3.y;
            }
            for (; j < npair; ++j) {
                int i0 = pair_idx(sidx, j << 1, half);
                float2 v0 = __half22float2(*(const __half2*)(xh + ((size_t)(unsigned)i0 << 6) + c2));
                A0.x += v0.x; A0.y += v0.y;
            }
            if (n & 1) {
                int il = __builtin_amdgcn_ds_bpermute((n - 1) << 2, sidx);
                if (lane < 32) {
                    float2 v = __half22float2(*(const __half2*)(xh + ((size_t)(unsigned)il << 6) + c2));
                    A0.x += v.x; A0.y += v.y;
                }
            }
        }
        float2 A;
        A.x = (A0.x + A1.x) + (A2.x + A3.x);
        A.y = (A0.y + A1.y) + (A2.y + A3.y);
        A.x += __shfl_xor(A.x, 32, 64);
        A.y += __shfl_xor(A.y, 32, 64);
#pragma unroll
        for (int off = 32; off > 0; off >>= 1) sumtau += __shfl_down(sumtau, off, 64);

        float inv = 1.f / fmaxf((float)d, 1.f);
        if (lane < 32)
            ((__half2*)(zm1 + (size_t)node * 64))[lane] =
                __floats2half2_rn(A.x * inv, A.y * inv);
        if (lane == 0) mt1[node] = __float2half(sumtau * inv);
    }
}

// zm2[node][64] = mean_h1 (fp16)
__global__ __launch_bounds__(LAYER_BLOCK) void k_aggr2(
    const __half* __restrict__ h1,
    const int* __restrict__ rowptr, const int* __restrict__ deg,
    const int* __restrict__ colidx, __half* __restrict__ zm2, int N) {
    int lane = threadIdx.x & 63;
    int half = lane >> 5;
    int c2 = (lane & 31) << 1;
    int wave = blockIdx.x * WAVES_PER_BLOCK + (threadIdx.x >> 6);
    int nwaves = gridDim.x * WAVES_PER_BLOCK;

    for (int node = wave; node < N; node += nwaves) {
        int start = rowptr[node];
        int d = deg[node];
        float2 A0 = {0.f, 0.f}, A1 = {0.f, 0.f}, A2 = {0.f, 0.f}, A3 = {0.f, 0.f};
        for (int base = 0; base < d; base += 64) {
            int n = d - base;
            if (n > 64) n = 64;
            int sidx = 0;
            if (lane < n) sidx = colidx[start + base + lane];
            int npair = n >> 1;
            int j = 0;
            for (; j + 4 <= npair; j += 4) {
                int i0 = pair_idx(sidx, (j + 0) << 1, half);
                int i1 = pair_idx(sidx, (j + 1) << 1, half);
                int i2 = pair_idx(sidx, (j + 2) << 1, half);
                int i3 = pair_idx(sidx, (j + 3) << 1, half);
                float2 v0 = __half22float2(*(const __half2*)(h1 + ((size_t)(unsigned)i0 << 6) + c2));
                float2 v1 = __half22float2(*(const __half2*)(h1 + ((size_t)(unsigned)i1 << 6) + c2));
                float2 v2 = __half22float2(*(const __half2*)(h1 + ((size_t)(unsigned)i2 << 6) + c2));
                float2 v3 = __half22float2(*(const __half2*)(h1 + ((size_t)(unsigned)i3 << 6) + c2));
                A0.x += v0.x; A0.y += v0.y;
                A1.x += v1.x; A1.y += v1.y;
                A2.x += v2.x; A2.y += v2.y;
                A3.x += v3.x; A3.y += v3.y;
            }
            for (; j < npair; ++j) {
                int i0 = pair_idx(sidx, j << 1, half);
                float2 v0 = __half22float2(*(const __half2*)(h1 + ((size_t)(unsigned)i0 << 6) + c2));
                A0.x += v0.x; A0.y += v0.y;
            }
            if (n & 1) {
                int il = __builtin_amdgcn_ds_bpermute((n - 1) << 2, sidx);
                if (lane < 32) {
                    float2 v = __half22float2(*(const __half2*)(h1 + ((size_t)(unsigned)il << 6) + c2));
                    A0.x += v.x; A0.y += v.y;
                }
            }
        }
        float2 A;
        A.x = (A0.x + A1.x) + (A2.x + A3.x);
        A.y = (A0.y + A1.y) + (A2.y + A3.y);
        A.x += __shfl_xor(A.x, 32, 64);
        A.y += __shfl_xor(A.y, 32, 64);
        float inv = 1.f / fmaxf((float)d, 1.f);
        if (lane < 32)
            ((__half2*)(zm2 + (size_t)node * 64))[lane] =
                __floats2half2_rn(A.x * inv, A.y * inv);
    }
}

// ---------------- MFMA GEMM kernels ----------------
// A frag: lane = m + 16*quad holds A[m][quad*8+j], contiguous 16B.
// C frag: col = lane&15, row = (lane>>4)*4 + reg. (validated in R6)

// h1 = relu([zm1 | xh | mtau,tau,0..] @ Wcat1 + b1l), fp16 out
__global__ __launch_bounds__(256) void k_gemm1(
    const __half* __restrict__ zm1, const __half* __restrict__ mt1,
    const __half* __restrict__ xh, const float* __restrict__ tau,
    const __half* __restrict__ wbuf1, const float* __restrict__ b1l,
    __half* __restrict__ h1, int ntiles) {
    int tile = blockIdx.x * 4 + (threadIdx.x >> 6);
    if (tile >= ntiles) return;
    int lane = threadIdx.x & 63;
    int sub = lane & 15;
    int quad = lane >> 4;
    int row = tile * 16 + sub;

    floatx4 acc0 = {0.f, 0.f, 0.f, 0.f};
    floatx4 acc1 = {0.f, 0.f, 0.f, 0.f};
    floatx4 acc2 = {0.f, 0.f, 0.f, 0.f};
    floatx4 acc3 = {0.f, 0.f, 0.f, 0.f};

    const _Float16* zrow = (const _Float16*)zm1 + (size_t)row * 64 + quad * 8;
    const _Float16* xrow = (const _Float16*)xh + (size_t)row * 64 + quad * 8;
    const _Float16* wb = (const _Float16*)wbuf1 + (size_t)lane * 8;

    half8 amat[5];
    amat[0] = *(const half8*)(zrow);
    amat[1] = *(const half8*)(zrow + 32);
    amat[2] = *(const half8*)(xrow);
    amat[3] = *(const half8*)(xrow + 32);
    half8 a4 = {0, 0, 0, 0, 0, 0, 0, 0};
    if (quad == 0) {
        a4[0] = ((const _Float16*)mt1)[row];
        a4[1] = (_Float16)tau[row];
    }
    amat[4] = a4;

#pragma unroll
    for (int ks = 0; ks < 5; ++ks) {
        half8 a = amat[ks];
        half8 b0 = *(const half8*)(wb + (size_t)(ks * 4 + 0) * 512);
        half8 b1 = *(const half8*)(wb + (size_t)(ks * 4 + 1) * 512);
        half8 b2 = *(const half8*)(wb + (size_t)(ks * 4 + 2) * 512);
        half8 b3 = *(const half8*)(wb + (size_t)(ks * 4 + 3) * 512);
        acc0 = __builtin_amdgcn_mfma_f32_16x16x32_f16(a, b0, acc0, 0, 0, 0);
        acc1 = __builtin_amdgcn_mfma_f32_16x16x32_f16(a, b1, acc1, 0, 0, 0);
        acc2 = __builtin_amdgcn_mfma_f32_16x16x32_f16(a, b2, acc2, 0, 0, 0);
        acc3 = __builtin_amdgcn_mfma_f32_16x16x32_f16(a, b3, acc3, 0, 0, 0);
    }
    float bv0 = b1l[sub], bv1 = b1l[16 + sub], bv2 = b1l[32 + sub], bv3 = b1l[48 + sub];
#pragma unroll
    for (int reg = 0; reg < 4; ++reg) {
        int r = quad * 4 + reg;
        __half* orow = h1 + (size_t)(tile * 16 + r) * 64;
        orow[sub]      = __float2half(fmaxf(acc0[reg] + bv0, 0.f));
        orow[16 + sub] = __float2half(fmaxf(acc1[reg] + bv1, 0.f));
        orow[32 + sub] = __float2half(fmaxf(acc2[reg] + bv2, 0.f));
        orow[48 + sub] = __float2half(fmaxf(acc3[reg] + bv3, 0.f));
    }
}

// out = relu([zm2 | h1] @ Wcat2 + b2l) @ Wfc + bfc
__global__ __launch_bounds__(256) void k_gemm2(
    const __half* __restrict__ zm2, const __half* __restrict__ h1,
    const __half* __restrict__ wbuf2, const float* __restrict__ b2l,
    const float* __restrict__ Wfc, const float* __restrict__ bfc,
    float* __restrict__ out, int ntiles) {
    int tile = blockIdx.x * 4 + (threadIdx.x >> 6);
    if (tile >= ntiles) return;
    int lane = threadIdx.x & 63;
    int sub = lane & 15;
    int quad = lane >> 4;
    int row = tile * 16 + sub;

    floatx4 acc0 = {0.f, 0.f, 0.f, 0.f};
    floatx4 acc1 = {0.f, 0.f, 0.f, 0.f};
    floatx4 acc2 = {0.f, 0.f, 0.f, 0.f};
    floatx4 acc3 = {0.f, 0.f, 0.f, 0.f};

    const _Float16* zrow = (const _Float16*)zm2 + (size_t)row * 64 + quad * 8;
    const _Float16* hrow = (const _Float16*)h1 + (size_t)row * 64 + quad * 8;
    const _Float16* wb = (const _Float16*)wbuf2 + (size_t)lane * 8;

    half8 amat[4];
    amat[0] = *(const half8*)(zrow);
    amat[1] = *(const half8*)(zrow + 32);
    amat[2] = *(const half8*)(hrow);
    amat[3] = *(const half8*)(hrow + 32);

#pragma unroll
    for (int ks = 0; ks < 4; ++ks) {
        half8 a = amat[ks];
        half8 b0 = *(const half8*)(wb + (size_t)(ks * 4 + 0) * 512);
        half8 b1 = *(const half8*)(wb + (size_t)(ks * 4 + 1) * 512);
        half8 b2 = *(const half8*)(wb + (size_t)(ks * 4 + 2) * 512);
        half8 b3 = *(const half8*)(wb + (size_t)(ks * 4 + 3) * 512);
        acc0 = __builtin_amdgcn_mfma_f32_16x16x32_f16(a, b0, acc0, 0, 0, 0);
        acc1 = __builtin_amdgcn_mfma_f32_16x16x32_f16(a, b1, acc1, 0, 0, 0);
        acc2 = __builtin_amdgcn_mfma_f32_16x16x32_f16(a, b2, acc2, 0, 0, 0);
        acc3 = __builtin_amdgcn_mfma_f32_16x16x32_f16(a, b3, acc3, 0, 0, 0);
    }
    float bb0 = b2l[sub], bb1 = b2l[16 + sub], bb2 = b2l[32 + sub], bb3 = b2l[48 + sub];
    float wv0 = Wfc[sub], wv1 = Wfc[16 + sub], wv2 = Wfc[32 + sub], wv3 = Wfc[48 + sub];
    float p[4];
#pragma unroll
    for (int reg = 0; reg < 4; ++reg) {
        p[reg] = fmaxf(acc0[reg] + bb0, 0.f) * wv0
               + fmaxf(acc1[reg] + bb1, 0.f) * wv1
               + fmaxf(acc2[reg] + bb2, 0.f) * wv2
               + fmaxf(acc3[reg] + bb3, 0.f) * wv3;
    }
#pragma unroll
    for (int m = 1; m <= 8; m <<= 1) {
#pragma unroll
        for (int reg = 0; reg < 4; ++reg) p[reg] += __shfl_xor(p[reg], m, 64);
    }
    if (sub == 0) {
        float b0 = bfc[0];
#pragma unroll
        for (int reg = 0; reg < 4; ++reg)
            out[tile * 16 + quad * 4 + reg] = p[reg] + b0;
    }
}

extern "C" void kernel_launch(void* const* d_in, const int* in_sizes, int n_in,
                              void* d_out, int out_size, void* d_ws, size_t ws_size,
                              hipStream_t stream) {
    const float* x   = (const float*)d_in[0];
    const int*   ei  = (const int*)d_in[1];
    const float* tau = (const float*)d_in[2];
    const float* W1l = (const float*)d_in[3];
    const float* b1l = (const float*)d_in[4];
    const float* W1r = (const float*)d_in[5];
    const float* W2l = (const float*)d_in[6];
    const float* b2l = (const float*)d_in[7];
    const float* W2r = (const float*)d_in[8];
    const float* Wfc = (const float*)d_in[9];
    const float* bfc = (const float*)d_in[10];
    float* out = (float*)d_out;

    const int N = in_sizes[0] / 64;   // 100000
    const int E = in_sizes[1] / 2;    // 3200000
    const int* src = ei;
    const int* dst = ei + E;

    char* w = (char*)d_ws;
    auto take = [&](size_t b) { char* p = w; w += (b + 255) & ~(size_t)255; return p; };
    int*    histT  = (int*)take((size_t)NBKT * NBLK * 4);
    int*    btot   = (int*)take((size_t)NBKT * 4);
    int*    bstart = (int*)take((size_t)(NBKT + 1) * 4);
    int*    binned = (int*)take((size_t)E * 4);
    int*    rowptr = (int*)take((size_t)N * 4);
    int*    deg    = (int*)take((size_t)N * 4);
    int*    colidx = (int*)take((size_t)E * 4);
    __half* xh     = (__half*)take((size_t)N * 64 * 2);    // 12.8 MB
    __half* h1     = (__half*)take((size_t)N * 64 * 2);    // 12.8 MB
    __half* zm1    = (__half*)take((size_t)N * 64 * 2);    // 12.8 MB
    __half* mt1    = (__half*)take((size_t)N * 2);
    __half* zm2    = (__half*)take((size_t)N * 64 * 2);    // 12.8 MB
    __half* wbuf1  = (__half*)take(1280 * 8 * 2);          // 20 KB
    __half* wbuf2  = (__half*)take(1024 * 8 * 2);          // 16 KB

    int n2 = N * 32;                  // half2 elements for prep
    int ntiles = N / 16;              // 6250 (exact)
    int gblocks = (ntiles + 3) / 4;   // 1563

    k_hist   <<<NBLK, 256, 0, stream>>>(dst, histT, E);
    k_scanblk<<<NBKT, NBLK, 0, stream>>>(histT, btot);
    k_scanbkt<<<1, 1024, 0, stream>>>(btot, bstart);
    k_scatter<<<NBLK, 256, 0, stream>>>(src, dst, histT, bstart, binned, E);
    k_bucket <<<NBKT, 256, 0, stream>>>(binned, bstart, rowptr, deg, colidx, N);
    k_prep   <<<(n2 + 255) / 256, 256, 0, stream>>>(x, xh, n2);
    k_prepw  <<<9, 256, 0, stream>>>(W1l, W1r, W2l, W2r, wbuf1, wbuf2);
    k_aggr1  <<<LAYER_GRID, LAYER_BLOCK, 0, stream>>>(xh, tau, rowptr, deg, colidx, zm1, mt1, N);
    k_gemm1  <<<gblocks, 256, 0, stream>>>(zm1, mt1, xh, tau, wbuf1, b1l, h1, ntiles);
    k_aggr2  <<<LAYER_GRID, LAYER_BLOCK, 0, stream>>>(h1, rowptr, deg, colidx, zm2, N);
    k_gemm2  <<<gblocks, 256, 0, stream>>>(zm2, h1, wbuf2, b2l, Wfc, bfc, out, ntiles);
}